// Round 2
// baseline (778.521 us; speedup 1.0000x reference)
//
#include <hip/hip_runtime.h>
#include <math.h>

#define NT 100000
#define B_GRAPHS 50
#define NE 1600000
#define V 15000
#define D 128
#define NODES_PER_GRAPH (NT / B_GRAPHS)   // 2000

#define CHUNK 1024
#define NCHUNK ((NT + CHUNK - 1) / CHUNK) // 98

// ---------- K1: P1 = embeds @ W1 + b1  [V,128] ----------
// 16 KB LDS (32 embed rows); W1 streamed coalesced, reused across 32 rows in regs.
#define PROJ_ROWS 32
__global__ void k_project(const float* __restrict__ embeds,
                          const float* __restrict__ W1,
                          const float* __restrict__ b1,
                          float* __restrict__ P1) {
  __shared__ float sE[PROJ_ROWS][D];   // 16 KB
  int t = threadIdx.x;                 // 0..127 = output column
  int row0 = blockIdx.x * PROJ_ROWS;
  for (int i = t; i < PROJ_ROWS * D; i += 128) {
    int r = i >> 7, c = i & 127;
    int v = row0 + r;
    sE[r][c] = (v < V) ? embeds[(size_t)v * D + c] : 0.f;
  }
  __syncthreads();
  float bd = b1[t];
  float acc[PROJ_ROWS];
#pragma unroll
  for (int r = 0; r < PROJ_ROWS; ++r) acc[r] = bd;
#pragma unroll 4
  for (int k = 0; k < D; ++k) {
    float w = W1[k * D + t];           // coalesced; L2-resident (64 KB total)
#pragma unroll
    for (int r = 0; r < PROJ_ROWS; ++r) acc[r] = fmaf(sE[r][k], w, acc[r]);
  }
  for (int r = 0; r < PROJ_ROWS; ++r) {
    int v = row0 + r;
    if (v < V) P1[(size_t)v * D + t] = acc[r];
  }
}

// ---------- K2: in-degree counts ----------
__global__ void k_count(const int* __restrict__ dst, int* __restrict__ counts) {
  int e = blockIdx.x * blockDim.x + threadIdx.x;
  if (e < NE) atomicAdd(&counts[dst[e]], 1);
}

// ---------- K3: per-chunk sums (chunk = 1024 counts) ----------
__global__ void k_chunksum(const int* __restrict__ counts, int* __restrict__ chunkSum) {
  __shared__ int red[256];
  int c = blockIdx.x, t = threadIdx.x;
  int base = c * CHUNK + t * 4;
  int s = 0;
#pragma unroll
  for (int i = 0; i < 4; ++i) { int idx = base + i; if (idx < NT) s += counts[idx]; }
  red[t] = s; __syncthreads();
  for (int off = 128; off > 0; off >>= 1) {
    if (t < off) red[t] += red[t + off];
    __syncthreads();
  }
  if (t == 0) chunkSum[c] = red[0];
}

// ---------- K4: exclusive scan of the 98 chunk sums ----------
__global__ void k_scanchunks(const int* __restrict__ chunkSum, int* __restrict__ chunkOff) {
  __shared__ int s[128];
  int t = threadIdx.x;                 // 128 threads
  int v = (t < NCHUNK) ? chunkSum[t] : 0;
  s[t] = v; __syncthreads();
  for (int off = 1; off < 128; off <<= 1) {
    int x = (t >= off) ? s[t - off] : 0;
    __syncthreads();
    s[t] += x;
    __syncthreads();
  }
  if (t < NCHUNK) chunkOff[t] = s[t] - v;   // exclusive
}

// ---------- K5: exclusive scan within chunk -> row_start ----------
__global__ void k_scan_write(const int* __restrict__ counts, const int* __restrict__ chunkOff,
                             int* __restrict__ row_start) {
  __shared__ int s[256];
  int c = blockIdx.x, t = threadIdx.x;
  int base = c * CHUNK + t * 4;
  int c0 = 0, c1 = 0, c2 = 0, c3 = 0;
  if (base + 0 < NT) c0 = counts[base + 0];
  if (base + 1 < NT) c1 = counts[base + 1];
  if (base + 2 < NT) c2 = counts[base + 2];
  if (base + 3 < NT) c3 = counts[base + 3];
  int tsum = c0 + c1 + c2 + c3;
  s[t] = tsum; __syncthreads();
  for (int off = 1; off < 256; off <<= 1) {
    int x = (t >= off) ? s[t - off] : 0;
    __syncthreads();
    s[t] += x;
    __syncthreads();
  }
  int toff = s[t] - tsum + chunkOff[c];
  if (base + 0 < NT) row_start[base + 0] = toff;
  if (base + 1 < NT) row_start[base + 1] = toff + c0;
  if (base + 2 < NT) row_start[base + 2] = toff + c0 + c1;
  if (base + 3 < NT) row_start[base + 3] = toff + c0 + c1 + c2;
}

// ---------- K6: fill CSR payload (src, edge_weight bits) ----------
__global__ void k_fill(const int* __restrict__ src, const int* __restrict__ dst,
                       const float* __restrict__ ew,
                       const int* __restrict__ row_start, int* __restrict__ cursor,
                       int2* __restrict__ esrc_ew) {
  int e = blockIdx.x * blockDim.x + threadIdx.x;
  if (e >= NE) return;
  int d = dst[e];
  int pos = row_start[d] + atomicAdd(&cursor[d], 1);
  esrc_ew[pos] = make_int2(src[e], __float_as_int(ew[e]));
}

// ---------- K7: layer-1 aggregate + mean + leaky_relu -> h1 ----------
// one wave per dst node; lane holds dims (2*lane, 2*lane+1)
__global__ void k_agg1(const int2* __restrict__ esrc_ew,
                       const int* __restrict__ row_start, const int* __restrict__ counts,
                       const int* __restrict__ node_ids,
                       const float* __restrict__ P1,
                       float* __restrict__ h1) {
  int n = blockIdx.x * 4 + (threadIdx.x >> 6);
  int lane = threadIdx.x & 63;
  int beg = row_start[n];
  int cnt = counts[n];
  float ax = 0.f, ay = 0.f;
  int2 pr = make_int2(0, 0); int wid = 0;
  if (cnt > 0) { pr = esrc_ew[beg]; wid = node_ids[pr.x]; }
  for (int j = 0; j < cnt; ++j) {
    int2 prn = make_int2(0, 0); int widn = 0;
    if (j + 1 < cnt) { prn = esrc_ew[beg + j + 1]; widn = node_ids[prn.x]; }
    float w = __int_as_float(pr.y);
    float2 v = ((const float2*)(P1 + (size_t)wid * D))[lane];
    ax = fmaf(w, v.x, ax);
    ay = fmaf(w, v.y, ay);
    pr = prn; wid = widn;
  }
  float inv = (cnt > 0) ? (1.0f / (float)cnt) : 0.0f;
  float x0 = ax * inv, x1 = ay * inv;
  x0 = (x0 > 0.f) ? x0 : 0.01f * x0;   // leaky_relu(0)=0 so deg==0 rows stay 0
  x1 = (x1 > 0.f) ? x1 : 0.01f * x1;
  ((float2*)(h1 + (size_t)n * D))[lane] = make_float2(x0, x1);
}

// ---------- K8: layer-2 aggregate fused with per-graph pooling ----------
// pool needs only S_g = sum_n agg(h1)[n] and Sc_g = sum_n (sum_ew/deg)[n]
#define NPW 5                                           // nodes per wave
#define BLOCKS_PER_GRAPH (NODES_PER_GRAPH / (4 * NPW))  // 100
__global__ void k_agg2(const int2* __restrict__ esrc_ew,
                       const int* __restrict__ row_start, const int* __restrict__ counts,
                       const float* __restrict__ h1,
                       float* __restrict__ poolS, float* __restrict__ poolC) {
  int g = blockIdx.x / BLOCKS_PER_GRAPH;
  int chunk = blockIdx.x % BLOCKS_PER_GRAPH;
  int w = threadIdx.x >> 6, lane = threadIdx.x & 63;
  int nbase = g * NODES_PER_GRAPH + chunk * (4 * NPW) + w * NPW;
  float sx = 0.f, sy = 0.f, sc = 0.f;
  for (int i = 0; i < NPW; ++i) {
    int n = nbase + i;
    int beg = row_start[n], cnt = counts[n];
    float ax = 0.f, ay = 0.f, sw = 0.f;
    int2 pr = make_int2(0, 0);
    if (cnt > 0) pr = esrc_ew[beg];
    for (int j = 0; j < cnt; ++j) {
      int2 prn = make_int2(0, 0);
      if (j + 1 < cnt) prn = esrc_ew[beg + j + 1];
      float wgt = __int_as_float(pr.y);
      float2 v = ((const float2*)(h1 + (size_t)pr.x * D))[lane];
      ax = fmaf(wgt, v.x, ax);
      ay = fmaf(wgt, v.y, ay);
      sw += wgt;
      pr = prn;
    }
    if (cnt > 0) {
      float inv = 1.0f / (float)cnt;
      sx += ax * inv; sy += ay * inv; sc += sw * inv;
    }
  }
  __shared__ float sS[256 * 2];
  __shared__ float sCred[256];
  sS[threadIdx.x * 2]     = sx;
  sS[threadIdx.x * 2 + 1] = sy;
  // sc is identical across all 64 lanes of a wave (scalar per node list):
  // only lane 0 may contribute, else the block reduce over-counts by 64x.
  sCred[threadIdx.x] = (lane == 0) ? sc : 0.f;
  __syncthreads();
  if (threadIdx.x < 64) {
    float x0 = 0.f, x1 = 0.f;
    for (int ww = 0; ww < 4; ++ww) {
      x0 += sS[(ww * 64 + threadIdx.x) * 2];
      x1 += sS[(ww * 64 + threadIdx.x) * 2 + 1];
    }
    atomicAdd(&poolS[g * D + 2 * threadIdx.x],     x0);
    atomicAdd(&poolS[g * D + 2 * threadIdx.x + 1], x1);
  }
  for (int off = 128; off > 0; off >>= 1) {
    if (threadIdx.x < off) sCred[threadIdx.x] += sCred[threadIdx.x + off];
    __syncthreads();
  }
  if (threadIdx.x == 0) atomicAdd(&poolC[g], sCred[0]);
}

// ---------- K9: head: logits = (S/2000)@(W2@W_out) + (Sc/2000)*(b2.W_out) + b_out ----------
__global__ void k_final(const float* __restrict__ poolS, const float* __restrict__ poolC,
                        const float* __restrict__ W2, const float* __restrict__ b2,
                        const float* __restrict__ W_out, const float* __restrict__ b_out,
                        const float* __restrict__ y, float* __restrict__ out) {
  int t = threadIdx.x;  // 128 threads
  __shared__ float w2o[D];
  __shared__ float red[D];
  __shared__ float s2o_sh;
  __shared__ float logits[B_GRAPHS];
  float acc = 0.f;
  for (int d = 0; d < D; ++d) acc = fmaf(W2[t * D + d], W_out[d], acc);
  w2o[t] = acc;
  red[t] = b2[t] * W_out[t];
  __syncthreads();
  for (int off = 64; off > 0; off >>= 1) {
    if (t < off) red[t] += red[t + off];
    __syncthreads();
  }
  if (t == 0) s2o_sh = red[0];
  __syncthreads();
  float s2o = s2o_sh;
  float bout = b_out[0];
  const float invN = 1.0f / (float)NODES_PER_GRAPH;
  for (int g = 0; g < B_GRAPHS; ++g) {
    red[t] = poolS[g * D + t] * w2o[t];
    __syncthreads();
    for (int off = 64; off > 0; off >>= 1) {
      if (t < off) red[t] += red[t + off];
      __syncthreads();
    }
    if (t == 0) logits[g] = red[0] * invN + poolC[g] * invN * s2o + bout;
    __syncthreads();
  }
  float term = 0.f;
  if (t < B_GRAPHS) {
    float l = logits[t];
    out[1 + t] = 1.0f / (1.0f + expf(-l));            // y_pred
    term = fmaxf(l, 0.f) - l * y[t] + log1pf(expf(-fabsf(l)));
  }
  red[t] = term;
  __syncthreads();
  for (int off = 64; off > 0; off >>= 1) {
    if (t < off) red[t] += red[t + off];
    __syncthreads();
  }
  if (t == 0) out[0] = red[0] / (float)B_GRAPHS;      // loss
}

extern "C" void kernel_launch(void* const* d_in, const int* in_sizes, int n_in,
                              void* d_out, int out_size, void* d_ws, size_t ws_size,
                              hipStream_t stream) {
  const int*   node_ids = (const int*)d_in[0];
  const int*   src      = (const int*)d_in[1];
  const int*   dst      = (const int*)d_in[2];
  const float* ew       = (const float*)d_in[3];
  const float* y        = (const float*)d_in[4];
  const float* embeds   = (const float*)d_in[5];
  const float* W1       = (const float*)d_in[6];
  const float* b1       = (const float*)d_in[7];
  const float* W2       = (const float*)d_in[8];
  const float* b2       = (const float*)d_in[9];
  const float* W_out    = (const float*)d_in[10];
  const float* b_out    = (const float*)d_in[11];
  float* out = (float*)d_out;
  (void)in_sizes; (void)n_in; (void)out_size; (void)ws_size;

  char* ws = (char*)d_ws;
  size_t off = 0;
  auto alloc = [&](size_t bytes) {
    size_t r = off;
    off = (off + bytes + 511) & ~(size_t)511;
    return r;
  };
  size_t o_counts = alloc((size_t)NT * 4);
  size_t o_cursor = alloc((size_t)NT * 4);
  size_t o_poolS  = alloc((size_t)B_GRAPHS * D * 4);
  size_t o_poolC  = alloc((size_t)B_GRAPHS * 4);
  size_t o_csum   = alloc(128 * 4);
  size_t o_coff   = alloc(128 * 4);
  size_t zero_end = off;                       // everything above must start at 0
  size_t o_rows   = alloc((size_t)NT * 4);
  size_t o_P1     = alloc((size_t)V * D * 4);
  size_t o_edges  = alloc((size_t)NE * 8);
  size_t o_h1     = alloc((size_t)NT * D * 4); // total ~73 MB

  int*   counts   = (int*)(ws + o_counts);
  int*   cursor   = (int*)(ws + o_cursor);
  float* poolS    = (float*)(ws + o_poolS);
  float* poolC    = (float*)(ws + o_poolC);
  int*   chunkSum = (int*)(ws + o_csum);
  int*   chunkOff = (int*)(ws + o_coff);
  int*   row_start= (int*)(ws + o_rows);
  float* P1       = (float*)(ws + o_P1);
  int2*  esrc_ew  = (int2*)(ws + o_edges);
  float* h1       = (float*)(ws + o_h1);

  // workspace is poisoned 0xAA before every call — zero the accumulators
  hipMemsetAsync(ws, 0, zero_end, stream);

  k_project<<<(V + PROJ_ROWS - 1) / PROJ_ROWS, 128, 0, stream>>>(embeds, W1, b1, P1);
  k_count<<<(NE + 255) / 256, 256, 0, stream>>>(dst, counts);
  k_chunksum<<<NCHUNK, 256, 0, stream>>>(counts, chunkSum);
  k_scanchunks<<<1, 128, 0, stream>>>(chunkSum, chunkOff);
  k_scan_write<<<NCHUNK, 256, 0, stream>>>(counts, chunkOff, row_start);
  k_fill<<<(NE + 255) / 256, 256, 0, stream>>>(src, dst, ew, row_start, cursor, esrc_ew);
  k_agg1<<<NT / 4, 256, 0, stream>>>(esrc_ew, row_start, counts, node_ids, P1, h1);
  k_agg2<<<B_GRAPHS * BLOCKS_PER_GRAPH, 256, 0, stream>>>(
      esrc_ew, row_start, counts, h1, poolS, poolC);
  k_final<<<1, 128, 0, stream>>>(poolS, poolC, W2, b2, W_out, b_out, y, out);
}